// Round 2
// baseline (672.193 us; speedup 1.0000x reference)
//
#include <hip/hip_runtime.h>

#define N_ATOMS 10000
#define N_PAIRS 250000
#define N_PROP 128
#define N_OUT 128

typedef float v4f __attribute__((ext_vector_type(4)));

// ---------------------------------------------------------------------------
// Phase A: ix[p,x,c] = (px[j,x,c] + diff[p,x]) * i1[p,c]   (96M f32, streaming)
// One float4 per thread. rows = p*3+x (750000 rows, 32 float4 each).
// Non-temporal store: ix is never re-read (phase E recomputes), keep L2/L3
// for i1 and px.
// ---------------------------------------------------------------------------
__global__ __launch_bounds__(256) void pair_ix_kernel(
    const int* __restrict__ ind2, const float* __restrict__ px,
    const float* __restrict__ i1, const float* __restrict__ diff,
    float* __restrict__ ix) {
  int e = blockIdx.x * 256 + threadIdx.x;   // float4 index, < 24,000,000
  int c4 = e & 31;                          // float4 within row
  int r = e >> 5;                           // row = p*3 + x
  int p = r / 3;
  int x = r - p * 3;
  int j = ind2[2 * p + 1];
  float d = diff[r];                        // diff[p*3+x] == diff[r]
  v4f s = ((const v4f*)i1)[p * 32 + c4];
  v4f v = ((const v4f*)px)[j * 96 + x * 32 + c4];
  v4f o = (v + d) * s;
  __builtin_nontemporal_store(o, ((v4f*)ix) + e);
}

// ---------------------------------------------------------------------------
// CSR bucketing of pairs by ind_i: histogram -> block scan -> fill
// ---------------------------------------------------------------------------
__global__ __launch_bounds__(256) void count_kernel(const int* __restrict__ ind2,
                                                    int* __restrict__ counts) {
  int p = blockIdx.x * 256 + threadIdx.x;
  if (p < N_PAIRS) atomicAdd(&counts[ind2[2 * p]], 1);
}

__global__ __launch_bounds__(256) void scan_kernel(const int* __restrict__ counts,
                                                   int* __restrict__ offsets) {
  const int T = 256, CH = 40;  // 256*40 = 10240 >= N_ATOMS
  int t = threadIdx.x;
  int base = t * CH;
  int local = 0;
  for (int i = 0; i < CH; ++i) {
    int idx = base + i;
    if (idx < N_ATOMS) local += counts[idx];
  }
  __shared__ int sums[T];
  sums[t] = local;
  __syncthreads();
  for (int off = 1; off < T; off <<= 1) {
    int v = (t >= off) ? sums[t - off] : 0;
    __syncthreads();
    sums[t] += v;
    __syncthreads();
  }
  int run = sums[t] - local;  // exclusive prefix
  for (int i = 0; i < CH; ++i) {
    int idx = base + i;
    if (idx < N_ATOMS) {
      offsets[idx] = run;
      run += counts[idx];
    }
  }
  if (t == T - 1) offsets[N_ATOMS] = sums[T - 1];
}

__global__ __launch_bounds__(256) void fill_kernel(
    const int* __restrict__ ind2, const int* __restrict__ offsets,
    int* __restrict__ cursor, int* __restrict__ bucket) {
  int p = blockIdx.x * 256 + threadIdx.x;
  if (p >= N_PAIRS) return;
  int a = ind2[2 * p];
  int pos = offsets[a] + atomicAdd(&cursor[a], 1);
  bucket[pos] = p;
}

// ---------------------------------------------------------------------------
// Phase E: per atom, recompute+accumulate seg[3][128] from its pairs (reads
// i1 rows coalesced, px rows via L2/L3), then fused 128x128 GEMM with w_pp
// (L2-resident, 64 KB) and dotted_px. One block of 128 threads per atom;
// thread t owns channel t.
// ---------------------------------------------------------------------------
__global__ __launch_bounds__(128) void atom_kernel(
    const int* __restrict__ ind2, const float* __restrict__ px,
    const float* __restrict__ i1, const float* __restrict__ diff,
    const float* __restrict__ w_pp, const int* __restrict__ offsets,
    const int* __restrict__ bucket,
    float* __restrict__ px_new, float* __restrict__ dotted) {
  int a = blockIdx.x;
  int t = threadIdx.x;  // 0..127 = prop channel
  int beg = offsets[a], end = offsets[a + 1];

  float acc0 = 0.f, acc1 = 0.f, acc2 = 0.f;
  for (int k = beg; k < end; ++k) {
    int p = bucket[k];
    int j = ind2[2 * p + 1];
    float s = i1[p * N_PROP + t];
    float d0 = diff[p * 3 + 0];
    float d1 = diff[p * 3 + 1];
    float d2 = diff[p * 3 + 2];
    const float* pj = px + j * 384;
    acc0 += (pj[t] + d0) * s;
    acc1 += (pj[128 + t] + d1) * s;
    acc2 += (pj[256 + t] + d2) * s;
  }

  __shared__ float seg[3][128];
  seg[0][t] = acc0;
  seg[1][t] = acc1;
  seg[2][t] = acc2;
  __syncthreads();

  float o0 = 0.f, o1 = 0.f, o2 = 0.f;
  for (int p = 0; p < 128; ++p) {
    float w = w_pp[p * 128 + t];   // coalesced, L2-resident
    float s0 = seg[0][p];          // LDS broadcast (conflict-free)
    float s1 = seg[1][p];
    float s2 = seg[2][p];
    o0 += s0 * w;
    o1 += s1 * w;
    o2 += s2 * w;
  }

  px_new[a * 384 + t]       = o0;
  px_new[a * 384 + 128 + t] = o1;
  px_new[a * 384 + 256 + t] = o2;
  dotted[a * 128 + t] = o0 * o0 + o1 * o1 + o2 * o2;
}

extern "C" void kernel_launch(void* const* d_in, const int* in_sizes, int n_in,
                              void* d_out, int out_size, void* d_ws, size_t ws_size,
                              hipStream_t stream) {
  const int* ind2    = (const int*)d_in[0];   // (250000,2) int32
  const float* px    = (const float*)d_in[1]; // (10000,3,128)
  const float* i1    = (const float*)d_in[2]; // (250000,128)
  const float* diff  = (const float*)d_in[3]; // (250000,3)
  const float* w_pp  = (const float*)d_in[4]; // (128,128)

  float* out_px_new = (float*)d_out;                          // 3,840,000
  float* out_ix     = out_px_new + (size_t)N_ATOMS * 3 * N_PROP;  // 96,000,000
  float* out_dot    = out_ix + (size_t)N_PAIRS * 3 * N_PROP;      // 1,280,000

  int* offsets = (int*)d_ws;               // N_ATOMS+1 (pad to +2)
  int* counts  = offsets + (N_ATOMS + 2);  // N_ATOMS
  int* cursor  = counts + N_ATOMS;         // N_ATOMS (contiguous with counts)
  int* bucket  = cursor + N_ATOMS;         // N_PAIRS

  // zero counts + cursor in one shot (ws is poisoned 0xAA before every call)
  (void)hipMemsetAsync(counts, 0, sizeof(int) * 2 * N_ATOMS, stream);

  pair_ix_kernel<<<93750, 256, 0, stream>>>(ind2, px, i1, diff, out_ix);
  count_kernel<<<(N_PAIRS + 255) / 256, 256, 0, stream>>>(ind2, counts);
  scan_kernel<<<1, 256, 0, stream>>>(counts, offsets);
  fill_kernel<<<(N_PAIRS + 255) / 256, 256, 0, stream>>>(ind2, offsets, cursor, bucket);
  atom_kernel<<<N_ATOMS, 128, 0, stream>>>(ind2, px, i1, diff, w_pp, offsets,
                                           bucket, out_px_new, out_dot);
}